// Round 12
// baseline (252.435 us; speedup 1.0000x reference)
//
#include <hip/hip_runtime.h>

// EquivariantGNN: 256 graphs, N=64 nodes, HID=64, fp32 in/out.
// R12: attack the ~1 wave/SIMD latency wall in edge_main (R11: clean traffic,
// 70us, Occ 10%). (1) launch_bounds(256,3): cap 170 total regs -> 3 waves/SIMD
// tier (arch ~106-138 + acc fits, unlike the 128-cap's 64/64 split).
// (2) 4 blocks/graph (1024 blocks, 16 nodes each) for CU fill slack.
// (3) dsq via shfl (kills a ds_write->read dep per iteration).

#define NG 256

typedef __attribute__((ext_vector_type(4))) float f32x4;
typedef __attribute__((ext_vector_type(8))) __bf16 bf16x8;

__device__ __forceinline__ f32x4 mfma16(bf16x8 a, bf16x8 b, f32x4 c){
  return __builtin_amdgcn_mfma_f32_16x16x32_bf16(a, b, c, 0, 0, 0);
}

// ws layout (bytes):
//   [0, 4M)            mi        f32 [256][64][64]
//   [4M, 6M)           a+b1      bf16 [256][64][64]
//   [6M, 8M)           c         bf16 [256][64][64]
//   [8M, 8M+8K)        W3^T      bf16 [64][64]   ([n'][k])
//   [8M+8K, 8M+16K)    W2^T      bf16 [64][64]   ([n][k])
//   [8M+16K, +256B)    cb1'      f32 [64]
#define WS_A   (4u<<20)
#define WS_C   (6u<<20)
#define WS_W3  (8u<<20)
#define WS_W2  ((8u<<20)+8192u)
#define WS_CB1 ((8u<<20)+16384u)

__global__ __launch_bounds__(256)
void egnn_pre(const float* __restrict__ x,
    const float* __restrict__ emb_w,  const float* __restrict__ emb_b,
    const float* __restrict__ edge_w1,const float* __restrict__ edge_b1,
    const float* __restrict__ edge_w2,const float* __restrict__ edge_b2,
    const float* __restrict__ coord_w1,const float* __restrict__ coord_b1,
    unsigned char* __restrict__ ws)
{
  __shared__ __align__(16) float sHt[64*64];   // h^T [m][i]
  __shared__ __align__(16) float sW [64*65];   // staged weight (padded)
  __shared__ float sXL[384], sEW[384], sEB[64], sB1[64];

  const int bs = blockIdx.x, tid = threadIdx.x;
  const float* xg = x + bs*384;
  __bf16* wsa = (__bf16*)(ws + WS_A) + bs*4096;
  __bf16* wsc = (__bf16*)(ws + WS_C) + bs*4096;

  for (int q=tid; q<384; q+=256){ sXL[q]=xg[q]; sEW[q]=emb_w[q]; }
  if (tid < 64){ sEB[tid]=emb_b[tid]; sB1[tid]=edge_b1[tid]; }
  __syncthreads();

  // h^T[m][i]
  #pragma unroll
  for (int e=0;e<16;e++){
    int idx=tid+e*256; int m=idx>>6, i=idx&63;
    float v = sEB[m];
    #pragma unroll
    for (int d=0;d<6;d++) v += sXL[i*6+d]*sEW[d*64+m];
    sHt[m*64+i] = v;
  }

  // ---- a = h@W1a + b1 -> bf16 ws ----
  #pragma unroll
  for (int e=0;e<16;e++){ int idx=tid+e*256;
    sW[(idx>>6)*65 + (idx&63)] = edge_w1[idx]; }
  __syncthreads();
  {
    const int tjx = tid>>5, tnx = tid&31;
    #pragma unroll
    for (int rb=0;rb<2;rb++){
      const int i0 = rb*32 + 4*tjx;
      float acc[4][2] = {};
      for (int m=0;m<64;m++){
        float4 av = *(const float4*)&sHt[m*64 + i0];
        float b0 = sW[m*65 + 2*tnx], b1v = sW[m*65 + 2*tnx + 1];
        acc[0][0]+=av.x*b0; acc[0][1]+=av.x*b1v;
        acc[1][0]+=av.y*b0; acc[1][1]+=av.y*b1v;
        acc[2][0]+=av.z*b0; acc[2][1]+=av.z*b1v;
        acc[3][0]+=av.w*b0; acc[3][1]+=av.w*b1v;
      }
      #pragma unroll
      for (int r=0;r<4;r++)
        #pragma unroll
        for (int c=0;c<2;c++)
          wsa[(i0+r)*64 + 2*tnx+c] = (__bf16)(acc[r][c] + sB1[2*tnx+c]);
    }
  }
  __syncthreads();

  // ---- c = h@W1b -> bf16 ws ----
  #pragma unroll
  for (int e=0;e<16;e++){ int idx=tid+e*256;
    sW[(idx>>6)*65 + (idx&63)] = edge_w1[4096 + idx]; }
  __syncthreads();
  {
    const int tjx = tid>>5, tnx = tid&31;
    #pragma unroll
    for (int rb=0;rb<2;rb++){
      const int i0 = rb*32 + 4*tjx;
      float acc[4][2] = {};
      for (int m=0;m<64;m++){
        float4 av = *(const float4*)&sHt[m*64 + i0];
        float b0 = sW[m*65 + 2*tnx], b1v = sW[m*65 + 2*tnx + 1];
        acc[0][0]+=av.x*b0; acc[0][1]+=av.x*b1v;
        acc[1][0]+=av.y*b0; acc[1][1]+=av.y*b1v;
        acc[2][0]+=av.z*b0; acc[2][1]+=av.z*b1v;
        acc[3][0]+=av.w*b0; acc[3][1]+=av.w*b1v;
      }
      #pragma unroll
      for (int r=0;r<4;r++)
        #pragma unroll
        for (int c=0;c<2;c++)
          wsc[(i0+r)*64 + 2*tnx+c] = (__bf16)acc[r][c];
    }
  }

  // ---- block 0 only: graph-invariant W3^T, W2^T, cb1' ----
  if (bs == 0){
    __syncthreads();
    #pragma unroll
    for (int e=0;e<16;e++){ int idx=tid+e*256;
      sW[(idx>>6)*65 + (idx&63)] = coord_w1[idx]; }   // cw1
    __syncthreads();
    {
      // W3[k][c] = sum_n W2[k][n]*cw1[n][c]; thread: k=tid>>2, 16 cols
      const int k = tid>>2, c0 = (tid&3)*16;
      float acc[16] = {};
      for (int n=0;n<64;n++){
        float w = edge_w2[k*64+n];
        #pragma unroll
        for (int cc=0;cc<16;cc+=4){
          float4 b = *(const float4*)&sW[n*65 + c0+cc];
          acc[cc]+=w*b.x; acc[cc+1]+=w*b.y; acc[cc+2]+=w*b.z; acc[cc+3]+=w*b.w;
        }
      }
      __bf16* w3t = (__bf16*)(ws + WS_W3);
      #pragma unroll
      for (int cc=0;cc<16;cc++) w3t[(c0+cc)*64 + k] = (__bf16)acc[cc];
    }
    { // W2^T
      __bf16* w2t = (__bf16*)(ws + WS_W2);
      #pragma unroll
      for (int e=0;e<16;e++){ int idx=tid+e*256; int n=idx>>6, k=idx&63;
        w2t[idx] = (__bf16)edge_w2[k*64+n]; }
    }
    if (tid < 64){ // cb1' = cb1 + b2@cw1
      float s = coord_b1[tid];
      for (int n=0;n<64;n++) s += edge_b2[n]*sW[n*65 + tid];
      ((float*)(ws + WS_CB1))[tid] = s;
    }
  }
}

__global__ __launch_bounds__(256, 3)
void egnn_edge_main(const float* __restrict__ x,
    const float* __restrict__ edge_w1, const float* __restrict__ edge_b2,
    const float* __restrict__ coord_w2,
    float* __restrict__ out, unsigned char* __restrict__ ws)
{
  __shared__ __align__(16) __bf16 sC  [64*72];
  __shared__ __align__(16) __bf16 sW3t[64*72];
  __shared__ __align__(16) __bf16 sW2t[64*72];
  __shared__ __align__(16) __bf16 sABb[16*72];
  __shared__ float sPX[64], sPY[64], sPZ[64];
  __shared__ __align__(16) float sW1L[64];
  __shared__ float sCB1p[64], sCW2[64], sB2[64];

  const int bx = blockIdx.x, tid = threadIdx.x;
  const int g = bx>>2, quarter = bx&3;
  const int lane = tid&63, wv = tid>>6, lg = lane>>4, ln = lane&15;
  const float* xg = x + g*384;

  // ---- stage ----
  {
    const bf16x8* pc = (const bf16x8*)((__bf16*)(ws + WS_C) + g*4096);
    const bf16x8* p3 = (const bf16x8*)(ws + WS_W3);
    const bf16x8* p2 = (const bf16x8*)(ws + WS_W2);
    const bf16x8* pa = (const bf16x8*)((__bf16*)(ws + WS_A) + g*4096 + quarter*1024);
    #pragma unroll
    for (int e=0;e<2;e++){
      int q = tid + e*256; int row=q>>3, c8=q&7;
      *(bf16x8*)&sC  [row*72 + c8*8] = pc[q];
      *(bf16x8*)&sW3t[row*72 + c8*8] = p3[q];
      *(bf16x8*)&sW2t[row*72 + c8*8] = p2[q];
    }
    if (tid < 128){ int q=tid; int row=q>>3, c8=q&7;
      *(bf16x8*)&sABb[row*72 + c8*8] = pa[q]; }
  }
  if (tid < 64){
    sW1L[tid]  = edge_w1[8192 + tid];
    sCB1p[tid] = ((const float*)(ws + WS_CB1))[tid];
    sCW2[tid]  = coord_w2[tid];
    sB2[tid]   = edge_b2[tid];
    sPX[tid]=xg[tid*6]; sPY[tid]=xg[tid*6+1]; sPZ[tid]=xg[tid*6+2];
  }
  __syncthreads();

  float* ws_mi = (float*)ws;

  // ---- main loop: wave wv owns node i = quarter*16 + ib*4 + wv ----
  for (int ib=0; ib<4; ib++){
    const int il = ib*4 + wv;          // local row in sABb
    const int i  = quarter*16 + il;    // global node id
    float dsqv;
    {
      float dx=sPX[i]-sPX[lane], dy=sPY[i]-sPY[lane], dz=sPZ[i]-sPZ[lane];
      dsqv = dx*dx+dy*dy+dz*dz;        // lane holds dsq for j=lane
    }
    bf16x8 abb[2];
    abb[0] = *(const bf16x8*)&sABb[il*72 + lg*8];
    abb[1] = *(const bf16x8*)&sABb[il*72 + 32 + lg*8];
    f32x4 accm[4];
    #pragma unroll
    for (int nt=0;nt<4;nt++) accm[nt] = f32x4{0.f,0.f,0.f,0.f};
    float sw=0.f, swx=0.f, swy=0.f, swz=0.f;

    #pragma unroll
    for (int jt=0;jt<4;jt++){
      const int j = jt*16 + ln;
      const float dq = __shfl(dsqv, j);   // dsq[j] via bpermute, no LDS dep
      f32x4 a4[4];
      #pragma unroll
      for (int nt=0;nt<4;nt++) a4[nt] = f32x4{0.f,0.f,0.f,0.f};

      #pragma unroll
      for (int kb=0;kb<2;kb++){
        const int k0 = kb*32 + lg*8;
        bf16x8 c8 = *(const bf16x8*)&sC[j*72 + k0];
        float w8[8];
        *(float4*)&w8[0] = *(const float4*)&sW1L[k0];
        *(float4*)&w8[4] = *(const float4*)&sW1L[k0+4];
        bf16x8 t8;
        #pragma unroll
        for (int e=0;e<8;e++){
          float v = (float)abb[kb][e] + (float)c8[e] + dq*w8[e];
          v = fmaxf(v, 0.f);
          t8[e] = (__bf16)v;
        }
        #pragma unroll
        for (int nt=0;nt<4;nt++){
          bf16x8 b3 = *(const bf16x8*)&sW3t[(nt*16+ln)*72 + k0];
          a4[nt] = mfma16(t8, b3, a4[nt]);
        }
        #pragma unroll
        for (int nt=0;nt<4;nt++){
          bf16x8 b2 = *(const bf16x8*)&sW2t[(nt*16+ln)*72 + k0];
          accm[nt] = mfma16(t8, b2, accm[nt]);
        }
      }

      // epilogue slice: w_j = relu(U+cb1')·cw2, 16-lane butterfly
      float wr[4];
      #pragma unroll
      for (int r=0;r<4;r++){
        float p = 0.f;
        #pragma unroll
        for (int nt=0;nt<4;nt++){
          int n = nt*16 + ln;
          float u = a4[nt][r] + sCB1p[n];
          p += fmaxf(u, 0.f)*sCW2[n];
        }
        p += __shfl_xor(p,1); p += __shfl_xor(p,2);
        p += __shfl_xor(p,4); p += __shfl_xor(p,8);
        wr[r] = p;
      }
      #pragma unroll
      for (int r=0;r<4;r++){
        int jj = jt*16 + lg*4 + r;
        sw  += wr[r];
        swx += wr[r]*sPX[jj];
        swy += wr[r]*sPY[jj];
        swz += wr[r]*sPZ[jj];
      }
    }

    // m_i = sum_j M[j][n] + 64*b2
    #pragma unroll
    for (int nt=0;nt<4;nt++){
      float s = accm[nt][0]+accm[nt][1]+accm[nt][2]+accm[nt][3];
      s += __shfl_xor(s,16); s += __shfl_xor(s,32);
      if (lg == 0){
        int n = nt*16 + ln;
        ws_mi[(g*64 + i)*64 + n] = s + 64.f*sB2[n];
      }
    }

    sw  += __shfl_xor(sw,16);  sw  += __shfl_xor(sw,32);
    swx += __shfl_xor(swx,16); swx += __shfl_xor(swx,32);
    swy += __shfl_xor(swy,16); swy += __shfl_xor(swy,32);
    swz += __shfl_xor(swz,16); swz += __shfl_xor(swz,32);
    if (lane == 0){
      float* o = out + (g*64 + i)*6;
      o[0] = sPX[i] + (sPX[i]*sw - swx)*(1.f/64.f);
      o[1] = sPY[i] + (sPY[i]*sw - swy)*(1.f/64.f);
      o[2] = sPZ[i] + (sPZ[i]*sw - swz)*(1.f/64.f);
    }
  }
}

// Node kernel: z = relu([h|mi]@nw1+nb1) via MFMA (K=128);
// vel_out = vel + h@fw3 + z@(nw2@fw3) + (nb2@fw3 + fb3).
__global__ __launch_bounds__(256)
void egnn_node_mfma(const float* __restrict__ x,
    const float* __restrict__ emb_w,  const float* __restrict__ emb_b,
    const float* __restrict__ node_w1,const float* __restrict__ node_b1,
    const float* __restrict__ node_w2,const float* __restrict__ node_b2,
    const float* __restrict__ final_w,const float* __restrict__ final_b,
    float* __restrict__ out, const float* __restrict__ ws_mi)
{
  __shared__ __align__(16) float  sHt [64*64];
  __shared__ __align__(16) __bf16 sAb [64*136];
  __shared__ __align__(16) __bf16 sNW1t[64*136];
  __shared__ __align__(16) float sNW2[64*64];
  __shared__ float sG  [64*4];
  __shared__ float sHf3[64*4];
  __shared__ float sFW3[64*4];
  __shared__ float sCvec[4];
  __shared__ float sXL[384], sEW[384], sEB[64], sNB1[64], sNB2[64];

  const int bs=blockIdx.x, tid=threadIdx.x;
  const int lane=tid&63, wv=tid>>6, ln=lane&15, lg=lane>>4;
  const float* xg = x + bs*384;

  for (int q=tid;q<384;q+=256){ sXL[q]=xg[q]; sEW[q]=emb_w[q]; }
  if (tid<64){ sEB[tid]=emb_b[tid]; sNB1[tid]=node_b1[tid]; sNB2[tid]=node_b2[tid]; }
  if (tid<192){ int n=tid&63, d=tid>>6; sFW3[n*4+d]=final_w[n*6+3+d]; }
  { const float4* g2=(const float4*)node_w2; float4* d2=(float4*)sNW2;
    #pragma unroll
    for (int e=0;e<4;e++) d2[tid+e*256]=g2[tid+e*256]; }
  #pragma unroll
  for (int e=0;e<32;e++){ int idx=tid+e*256; int kk=idx>>6, n=idx&63;
    sNW1t[n*136+kk]=(__bf16)node_w1[idx]; }
  { const float* mig = ws_mi + bs*4096;
    #pragma unroll
    for (int e=0;e<16;e++){ int idx=tid+e*256; int i=idx>>6, n=idx&63;
      sAb[i*136+64+n]=(__bf16)mig[idx]; } }
  __syncthreads();

  { int j=tid&63, mb=tid>>6;
    #pragma unroll
    for (int mm=0;mm<16;mm++){ int m=mb*16+mm;
      float v=sEB[m];
      #pragma unroll
      for (int d=0;d<6;d++) v+=sXL[j*6+d]*sEW[d*64+m];
      sHt[m*64+j]=v; sAb[j*136+m]=(__bf16)v; } }
  __syncthreads();

  if (tid<192){
    int k=tid&63, d=tid>>6;
    float gacc=0.f, s=0.f;
    for (int nn=0;nn<64;nn++){
      int n=(nn+k)&63;
      gacc += sNW2[k*64+n]*sFW3[n*4+d];
      s    += sHt[nn*64+k]*sFW3[nn*4+d];
    }
    sG[k*4+d]=gacc; sHf3[k*4+d]=s;
  } else if (tid<195){
    int d=tid-192; float c=final_b[3+d];
    for (int n=0;n<64;n++) c+=sNB2[n]*sFW3[n*4+d];
    sCvec[d]=c;
  }
  __syncthreads();

  f32x4 acc[4];
  #pragma unroll
  for (int nt=0;nt<4;nt++) acc[nt]=f32x4{0.f,0.f,0.f,0.f};
  #pragma unroll
  for (int kb=0;kb<4;kb++){
    bf16x8 a8 = *(const bf16x8*)&sAb[(wv*16+ln)*136 + kb*32 + lg*8];
    #pragma unroll
    for (int nt=0;nt<4;nt++){
      bf16x8 b8 = *(const bf16x8*)&sNW1t[(nt*16+ln)*136 + kb*32 + lg*8];
      acc[nt]=mfma16(a8,b8,acc[nt]);
    }
  }
  float p[4][3];
  #pragma unroll
  for(int r=0;r<4;r++){ p[r][0]=0.f; p[r][1]=0.f; p[r][2]=0.f; }
  #pragma unroll
  for (int nt=0;nt<4;nt++){
    int n=nt*16+ln;
    float zb=sNB1[n];
    float g0=sG[n*4], g1=sG[n*4+1], g2=sG[n*4+2];
    #pragma unroll
    for (int r=0;r<4;r++){
      float u=fmaxf(acc[nt][r]+zb,0.f);
      p[r][0]+=u*g0; p[r][1]+=u*g1; p[r][2]+=u*g2;
    }
  }
  #pragma unroll
  for (int off=1;off<16;off<<=1)
    #pragma unroll
    for (int r=0;r<4;r++){
      p[r][0]+=__shfl_xor(p[r][0],off);
      p[r][1]+=__shfl_xor(p[r][1],off);
      p[r][2]+=__shfl_xor(p[r][2],off);
    }
  if (ln==0){
    #pragma unroll
    for (int r=0;r<4;r++){
      int j=wv*16+lg*4+r; int base=(bs*64+j)*6;
      #pragma unroll
      for (int d=0;d<3;d++)
        out[base+3+d]=xg[j*6+3+d]+sHf3[j*4+d]+sCvec[d]+p[r][d];
    }
  }
}

extern "C" void kernel_launch(void* const* d_in, const int* in_sizes, int n_in,
                              void* d_out, int out_size, void* d_ws, size_t ws_size,
                              hipStream_t stream)
{
  const float* x        = (const float*)d_in[0];
  const float* emb_w    = (const float*)d_in[1];
  const float* emb_b    = (const float*)d_in[2];
  const float* edge_w1  = (const float*)d_in[3];
  const float* edge_b1  = (const float*)d_in[4];
  const float* edge_w2  = (const float*)d_in[5];
  const float* edge_b2  = (const float*)d_in[6];
  const float* node_w1  = (const float*)d_in[7];
  const float* node_b1  = (const float*)d_in[8];
  const float* node_w2  = (const float*)d_in[9];
  const float* node_b2  = (const float*)d_in[10];
  const float* coord_w1 = (const float*)d_in[11];
  const float* coord_b1 = (const float*)d_in[12];
  const float* coord_w2 = (const float*)d_in[13];
  const float* final_w  = (const float*)d_in[14];
  const float* final_b  = (const float*)d_in[15];
  float* out = (float*)d_out;
  unsigned char* ws = (unsigned char*)d_ws;   // uses ~8.02 MB

  egnn_pre<<<NG, 256, 0, stream>>>(x, emb_w, emb_b,
      edge_w1, edge_b1, edge_w2, edge_b2, coord_w1, coord_b1, ws);
  egnn_edge_main<<<4*NG, 256, 0, stream>>>(x, edge_w1, edge_b2, coord_w2,
      out, ws);
  egnn_node_mfma<<<NG, 256, 0, stream>>>(x, emb_w, emb_b,
      node_w1, node_b1, node_w2, node_b2, final_w, final_b,
      out, (const float*)ws);
}

// Round 13
// 77.628 us; speedup vs baseline: 3.2518x; 3.2518x over previous
//
#include <hip/hip_runtime.h>

// EquivariantGNN: 256 graphs, N=64 nodes, HID=64, fp32 in/out.
// R13: R12's structure WITHOUT the min-waves bound (R8/R9/R10/R12 all proved
// any forced min-waves -> 64-84 arch VGPR split -> catastrophic spill; R11
// no-bound -> 164 regs, clean). Grid 1024 blocks (4/graph) for fill + tail.
// Loop cuts: w18 hoisted to regs (invariant); deferred epilogue reduction
// (64 shfl/iter -> 24).

#define NG 256

typedef __attribute__((ext_vector_type(4))) float f32x4;
typedef __attribute__((ext_vector_type(8))) __bf16 bf16x8;

__device__ __forceinline__ f32x4 mfma16(bf16x8 a, bf16x8 b, f32x4 c){
  return __builtin_amdgcn_mfma_f32_16x16x32_bf16(a, b, c, 0, 0, 0);
}

// ws layout (bytes):
//   [0, 4M)            mi        f32 [256][64][64]
//   [4M, 6M)           a+b1      bf16 [256][64][64]
//   [6M, 8M)           c         bf16 [256][64][64]
//   [8M, 8M+8K)        W3^T      bf16 [64][64]   ([n'][k])
//   [8M+8K, 8M+16K)    W2^T      bf16 [64][64]   ([n][k])
//   [8M+16K, +256B)    cb1'      f32 [64]
#define WS_A   (4u<<20)
#define WS_C   (6u<<20)
#define WS_W3  (8u<<20)
#define WS_W2  ((8u<<20)+8192u)
#define WS_CB1 ((8u<<20)+16384u)

__global__ __launch_bounds__(256)
void egnn_pre(const float* __restrict__ x,
    const float* __restrict__ emb_w,  const float* __restrict__ emb_b,
    const float* __restrict__ edge_w1,const float* __restrict__ edge_b1,
    const float* __restrict__ edge_w2,const float* __restrict__ edge_b2,
    const float* __restrict__ coord_w1,const float* __restrict__ coord_b1,
    unsigned char* __restrict__ ws)
{
  __shared__ __align__(16) float sHt[64*64];   // h^T [m][i]
  __shared__ __align__(16) float sW [64*65];   // staged weight (padded)
  __shared__ float sXL[384], sEW[384], sEB[64], sB1[64];

  const int bs = blockIdx.x, tid = threadIdx.x;
  const float* xg = x + bs*384;
  __bf16* wsa = (__bf16*)(ws + WS_A) + bs*4096;
  __bf16* wsc = (__bf16*)(ws + WS_C) + bs*4096;

  for (int q=tid; q<384; q+=256){ sXL[q]=xg[q]; sEW[q]=emb_w[q]; }
  if (tid < 64){ sEB[tid]=emb_b[tid]; sB1[tid]=edge_b1[tid]; }
  __syncthreads();

  // h^T[m][i]
  #pragma unroll
  for (int e=0;e<16;e++){
    int idx=tid+e*256; int m=idx>>6, i=idx&63;
    float v = sEB[m];
    #pragma unroll
    for (int d=0;d<6;d++) v += sXL[i*6+d]*sEW[d*64+m];
    sHt[m*64+i] = v;
  }

  // ---- a = h@W1a + b1 -> bf16 ws ----
  #pragma unroll
  for (int e=0;e<16;e++){ int idx=tid+e*256;
    sW[(idx>>6)*65 + (idx&63)] = edge_w1[idx]; }
  __syncthreads();
  {
    const int tjx = tid>>5, tnx = tid&31;
    #pragma unroll
    for (int rb=0;rb<2;rb++){
      const int i0 = rb*32 + 4*tjx;
      float acc[4][2] = {};
      for (int m=0;m<64;m++){
        float4 av = *(const float4*)&sHt[m*64 + i0];
        float b0 = sW[m*65 + 2*tnx], b1v = sW[m*65 + 2*tnx + 1];
        acc[0][0]+=av.x*b0; acc[0][1]+=av.x*b1v;
        acc[1][0]+=av.y*b0; acc[1][1]+=av.y*b1v;
        acc[2][0]+=av.z*b0; acc[2][1]+=av.z*b1v;
        acc[3][0]+=av.w*b0; acc[3][1]+=av.w*b1v;
      }
      #pragma unroll
      for (int r=0;r<4;r++)
        #pragma unroll
        for (int c=0;c<2;c++)
          wsa[(i0+r)*64 + 2*tnx+c] = (__bf16)(acc[r][c] + sB1[2*tnx+c]);
    }
  }
  __syncthreads();

  // ---- c = h@W1b -> bf16 ws ----
  #pragma unroll
  for (int e=0;e<16;e++){ int idx=tid+e*256;
    sW[(idx>>6)*65 + (idx&63)] = edge_w1[4096 + idx]; }
  __syncthreads();
  {
    const int tjx = tid>>5, tnx = tid&31;
    #pragma unroll
    for (int rb=0;rb<2;rb++){
      const int i0 = rb*32 + 4*tjx;
      float acc[4][2] = {};
      for (int m=0;m<64;m++){
        float4 av = *(const float4*)&sHt[m*64 + i0];
        float b0 = sW[m*65 + 2*tnx], b1v = sW[m*65 + 2*tnx + 1];
        acc[0][0]+=av.x*b0; acc[0][1]+=av.x*b1v;
        acc[1][0]+=av.y*b0; acc[1][1]+=av.y*b1v;
        acc[2][0]+=av.z*b0; acc[2][1]+=av.z*b1v;
        acc[3][0]+=av.w*b0; acc[3][1]+=av.w*b1v;
      }
      #pragma unroll
      for (int r=0;r<4;r++)
        #pragma unroll
        for (int c=0;c<2;c++)
          wsc[(i0+r)*64 + 2*tnx+c] = (__bf16)acc[r][c];
    }
  }

  // ---- block 0 only: graph-invariant W3^T, W2^T, cb1' ----
  if (bs == 0){
    __syncthreads();
    #pragma unroll
    for (int e=0;e<16;e++){ int idx=tid+e*256;
      sW[(idx>>6)*65 + (idx&63)] = coord_w1[idx]; }   // cw1
    __syncthreads();
    {
      // W3[k][c] = sum_n W2[k][n]*cw1[n][c]; thread: k=tid>>2, 16 cols
      const int k = tid>>2, c0 = (tid&3)*16;
      float acc[16] = {};
      for (int n=0;n<64;n++){
        float w = edge_w2[k*64+n];
        #pragma unroll
        for (int cc=0;cc<16;cc+=4){
          float4 b = *(const float4*)&sW[n*65 + c0+cc];
          acc[cc]+=w*b.x; acc[cc+1]+=w*b.y; acc[cc+2]+=w*b.z; acc[cc+3]+=w*b.w;
        }
      }
      __bf16* w3t = (__bf16*)(ws + WS_W3);
      #pragma unroll
      for (int cc=0;cc<16;cc++) w3t[(c0+cc)*64 + k] = (__bf16)acc[cc];
    }
    { // W2^T
      __bf16* w2t = (__bf16*)(ws + WS_W2);
      #pragma unroll
      for (int e=0;e<16;e++){ int idx=tid+e*256; int n=idx>>6, k=idx&63;
        w2t[idx] = (__bf16)edge_w2[k*64+n]; }
    }
    if (tid < 64){ // cb1' = cb1 + b2@cw1
      float s = coord_b1[tid];
      for (int n=0;n<64;n++) s += edge_b2[n]*sW[n*65 + tid];
      ((float*)(ws + WS_CB1))[tid] = s;
    }
  }
}

__global__ __launch_bounds__(256)
void egnn_edge_main(const float* __restrict__ x,
    const float* __restrict__ edge_w1, const float* __restrict__ edge_b2,
    const float* __restrict__ coord_w2,
    float* __restrict__ out, unsigned char* __restrict__ ws)
{
  __shared__ __align__(16) __bf16 sC  [64*72];
  __shared__ __align__(16) __bf16 sW3t[64*72];
  __shared__ __align__(16) __bf16 sW2t[64*72];
  __shared__ __align__(16) __bf16 sABb[16*72];
  __shared__ float sPX[64], sPY[64], sPZ[64];
  __shared__ __align__(16) float sW1L[64];
  __shared__ float sCB1p[64], sCW2[64], sB2[64];

  const int bx = blockIdx.x, tid = threadIdx.x;
  const int g = bx>>2, quarter = bx&3;
  const int lane = tid&63, wv = tid>>6, lg = lane>>4, ln = lane&15;
  const float* xg = x + g*384;

  // ---- stage ----
  {
    const bf16x8* pc = (const bf16x8*)((__bf16*)(ws + WS_C) + g*4096);
    const bf16x8* p3 = (const bf16x8*)(ws + WS_W3);
    const bf16x8* p2 = (const bf16x8*)(ws + WS_W2);
    const bf16x8* pa = (const bf16x8*)((__bf16*)(ws + WS_A) + g*4096 + quarter*1024);
    #pragma unroll
    for (int e=0;e<2;e++){
      int q = tid + e*256; int row=q>>3, c8=q&7;
      *(bf16x8*)&sC  [row*72 + c8*8] = pc[q];
      *(bf16x8*)&sW3t[row*72 + c8*8] = p3[q];
      *(bf16x8*)&sW2t[row*72 + c8*8] = p2[q];
    }
    if (tid < 128){ int q=tid; int row=q>>3, c8=q&7;
      *(bf16x8*)&sABb[row*72 + c8*8] = pa[q]; }
  }
  if (tid < 64){
    sW1L[tid]  = edge_w1[8192 + tid];
    sCB1p[tid] = ((const float*)(ws + WS_CB1))[tid];
    sCW2[tid]  = coord_w2[tid];
    sB2[tid]   = edge_b2[tid];
    sPX[tid]=xg[tid*6]; sPY[tid]=xg[tid*6+1]; sPZ[tid]=xg[tid*6+2];
  }
  __syncthreads();

  float* ws_mi = (float*)ws;

  // loop-invariant w1L fragment (16 regs)
  float w18[2][8];
  #pragma unroll
  for (int kb=0;kb<2;kb++){
    *(float4*)&w18[kb][0] = *(const float4*)&sW1L[kb*32+lg*8];
    *(float4*)&w18[kb][4] = *(const float4*)&sW1L[kb*32+lg*8+4];
  }

  // ---- main loop: wave wv owns node i = quarter*16 + ib*4 + wv ----
  for (int ib=0; ib<4; ib++){
    const int il = ib*4 + wv;          // local row in sABb
    const int i  = quarter*16 + il;    // global node id
    float dsqv;
    {
      float dx=sPX[i]-sPX[lane], dy=sPY[i]-sPY[lane], dz=sPZ[i]-sPZ[lane];
      dsqv = dx*dx+dy*dy+dz*dz;        // lane holds dsq for j=lane
    }
    bf16x8 abb[2];
    abb[0] = *(const bf16x8*)&sABb[il*72 + lg*8];
    abb[1] = *(const bf16x8*)&sABb[il*72 + 32 + lg*8];
    f32x4 accm[4];
    #pragma unroll
    for (int nt=0;nt<4;nt++) accm[nt] = f32x4{0.f,0.f,0.f,0.f};
    float sw=0.f, swx=0.f, swy=0.f, swz=0.f;

    #pragma unroll
    for (int jt=0;jt<4;jt++){
      const int j = jt*16 + ln;
      const float dq = __shfl(dsqv, j);   // dsq[j], no LDS dep
      f32x4 a4[4];
      #pragma unroll
      for (int nt=0;nt<4;nt++) a4[nt] = f32x4{0.f,0.f,0.f,0.f};

      #pragma unroll
      for (int kb=0;kb<2;kb++){
        const int k0 = kb*32 + lg*8;
        bf16x8 c8 = *(const bf16x8*)&sC[j*72 + k0];
        bf16x8 t8;
        #pragma unroll
        for (int e=0;e<8;e++){
          float v = (float)abb[kb][e] + (float)c8[e] + dq*w18[kb][e];
          v = fmaxf(v, 0.f);
          t8[e] = (__bf16)v;
        }
        #pragma unroll
        for (int nt=0;nt<4;nt++){
          bf16x8 b3 = *(const bf16x8*)&sW3t[(nt*16+ln)*72 + k0];
          a4[nt] = mfma16(t8, b3, a4[nt]);
        }
        #pragma unroll
        for (int nt=0;nt<4;nt++){
          bf16x8 b2 = *(const bf16x8*)&sW2t[(nt*16+ln)*72 + k0];
          accm[nt] = mfma16(t8, b2, accm[nt]);
        }
      }

      // deferred epilogue: per-lane partials, NO per-jt reduction
      #pragma unroll
      for (int r=0;r<4;r++){
        float p = 0.f;
        #pragma unroll
        for (int nt=0;nt<4;nt++){
          int n = nt*16 + ln;
          float u = a4[nt][r] + sCB1p[n];
          p += fmaxf(u, 0.f)*sCW2[n];
        }
        int jj = jt*16 + lg*4 + r;
        sw  += p;
        swx += p*sPX[jj];
        swy += p*sPY[jj];
        swz += p*sPZ[jj];
      }
    }

    // m_i = sum_j M[j][n] + 64*b2
    #pragma unroll
    for (int nt=0;nt<4;nt++){
      float s = accm[nt][0]+accm[nt][1]+accm[nt][2]+accm[nt][3];
      s += __shfl_xor(s,16); s += __shfl_xor(s,32);
      if (lg == 0){
        int n = nt*16 + ln;
        ws_mi[(g*64 + i)*64 + n] = s + 64.f*sB2[n];
      }
    }

    // single full-wave butterfly for the 4 position sums
    #pragma unroll
    for (int off=1; off<64; off<<=1){
      sw  += __shfl_xor(sw, off);
      swx += __shfl_xor(swx, off);
      swy += __shfl_xor(swy, off);
      swz += __shfl_xor(swz, off);
    }
    if (lane == 0){
      float* o = out + (g*64 + i)*6;
      o[0] = sPX[i] + (sPX[i]*sw - swx)*(1.f/64.f);
      o[1] = sPY[i] + (sPY[i]*sw - swy)*(1.f/64.f);
      o[2] = sPZ[i] + (sPZ[i]*sw - swz)*(1.f/64.f);
    }
  }
}

// Node kernel: z = relu([h|mi]@nw1+nb1) via MFMA (K=128);
// vel_out = vel + h@fw3 + z@(nw2@fw3) + (nb2@fw3 + fb3).
__global__ __launch_bounds__(256)
void egnn_node_mfma(const float* __restrict__ x,
    const float* __restrict__ emb_w,  const float* __restrict__ emb_b,
    const float* __restrict__ node_w1,const float* __restrict__ node_b1,
    const float* __restrict__ node_w2,const float* __restrict__ node_b2,
    const float* __restrict__ final_w,const float* __restrict__ final_b,
    float* __restrict__ out, const float* __restrict__ ws_mi)
{
  __shared__ __align__(16) float  sHt [64*64];
  __shared__ __align__(16) __bf16 sAb [64*136];
  __shared__ __align__(16) __bf16 sNW1t[64*136];
  __shared__ __align__(16) float sNW2[64*64];
  __shared__ float sG  [64*4];
  __shared__ float sHf3[64*4];
  __shared__ float sFW3[64*4];
  __shared__ float sCvec[4];
  __shared__ float sXL[384], sEW[384], sEB[64], sNB1[64], sNB2[64];

  const int bs=blockIdx.x, tid=threadIdx.x;
  const int lane=tid&63, wv=tid>>6, ln=lane&15, lg=lane>>4;
  const float* xg = x + bs*384;

  for (int q=tid;q<384;q+=256){ sXL[q]=xg[q]; sEW[q]=emb_w[q]; }
  if (tid<64){ sEB[tid]=emb_b[tid]; sNB1[tid]=node_b1[tid]; sNB2[tid]=node_b2[tid]; }
  if (tid<192){ int n=tid&63, d=tid>>6; sFW3[n*4+d]=final_w[n*6+3+d]; }
  { const float4* g2=(const float4*)node_w2; float4* d2=(float4*)sNW2;
    #pragma unroll
    for (int e=0;e<4;e++) d2[tid+e*256]=g2[tid+e*256]; }
  #pragma unroll
  for (int e=0;e<32;e++){ int idx=tid+e*256; int kk=idx>>6, n=idx&63;
    sNW1t[n*136+kk]=(__bf16)node_w1[idx]; }
  { const float* mig = ws_mi + bs*4096;
    #pragma unroll
    for (int e=0;e<16;e++){ int idx=tid+e*256; int i=idx>>6, n=idx&63;
      sAb[i*136+64+n]=(__bf16)mig[idx]; } }
  __syncthreads();

  { int j=tid&63, mb=tid>>6;
    #pragma unroll
    for (int mm=0;mm<16;mm++){ int m=mb*16+mm;
      float v=sEB[m];
      #pragma unroll
      for (int d=0;d<6;d++) v+=sXL[j*6+d]*sEW[d*64+m];
      sHt[m*64+j]=v; sAb[j*136+m]=(__bf16)v; } }
  __syncthreads();

  if (tid<192){
    int k=tid&63, d=tid>>6;
    float gacc=0.f, s=0.f;
    for (int nn=0;nn<64;nn++){
      int n=(nn+k)&63;
      gacc += sNW2[k*64+n]*sFW3[n*4+d];
      s    += sHt[nn*64+k]*sFW3[nn*4+d];
    }
    sG[k*4+d]=gacc; sHf3[k*4+d]=s;
  } else if (tid<195){
    int d=tid-192; float c=final_b[3+d];
    for (int n=0;n<64;n++) c+=sNB2[n]*sFW3[n*4+d];
    sCvec[d]=c;
  }
  __syncthreads();

  f32x4 acc[4];
  #pragma unroll
  for (int nt=0;nt<4;nt++) acc[nt]=f32x4{0.f,0.f,0.f,0.f};
  #pragma unroll
  for (int kb=0;kb<4;kb++){
    bf16x8 a8 = *(const bf16x8*)&sAb[(wv*16+ln)*136 + kb*32 + lg*8];
    #pragma unroll
    for (int nt=0;nt<4;nt++){
      bf16x8 b8 = *(const bf16x8*)&sNW1t[(nt*16+ln)*136 + kb*32 + lg*8];
      acc[nt]=mfma16(a8,b8,acc[nt]);
    }
  }
  float p[4][3];
  #pragma unroll
  for(int r=0;r<4;r++){ p[r][0]=0.f; p[r][1]=0.f; p[r][2]=0.f; }
  #pragma unroll
  for (int nt=0;nt<4;nt++){
    int n=nt*16+ln;
    float zb=sNB1[n];
    float g0=sG[n*4], g1=sG[n*4+1], g2=sG[n*4+2];
    #pragma unroll
    for (int r=0;r<4;r++){
      float u=fmaxf(acc[nt][r]+zb,0.f);
      p[r][0]+=u*g0; p[r][1]+=u*g1; p[r][2]+=u*g2;
    }
  }
  #pragma unroll
  for (int off=1;off<16;off<<=1)
    #pragma unroll
    for (int r=0;r<4;r++){
      p[r][0]+=__shfl_xor(p[r][0],off);
      p[r][1]+=__shfl_xor(p[r][1],off);
      p[r][2]+=__shfl_xor(p[r][2],off);
    }
  if (ln==0){
    #pragma unroll
    for (int r=0;r<4;r++){
      int j=wv*16+lg*4+r; int base=(bs*64+j)*6;
      #pragma unroll
      for (int d=0;d<3;d++)
        out[base+3+d]=xg[j*6+3+d]+sHf3[j*4+d]+sCvec[d]+p[r][d];
    }
  }
}

extern "C" void kernel_launch(void* const* d_in, const int* in_sizes, int n_in,
                              void* d_out, int out_size, void* d_ws, size_t ws_size,
                              hipStream_t stream)
{
  const float* x        = (const float*)d_in[0];
  const float* emb_w    = (const float*)d_in[1];
  const float* emb_b    = (const float*)d_in[2];
  const float* edge_w1  = (const float*)d_in[3];
  const float* edge_b1  = (const float*)d_in[4];
  const float* edge_w2  = (const float*)d_in[5];
  const float* edge_b2  = (const float*)d_in[6];
  const float* node_w1  = (const float*)d_in[7];
  const float* node_b1  = (const float*)d_in[8];
  const float* node_w2  = (const float*)d_in[9];
  const float* node_b2  = (const float*)d_in[10];
  const float* coord_w1 = (const float*)d_in[11];
  const float* coord_b1 = (const float*)d_in[12];
  const float* coord_w2 = (const float*)d_in[13];
  const float* final_w  = (const float*)d_in[14];
  const float* final_b  = (const float*)d_in[15];
  float* out = (float*)d_out;
  unsigned char* ws = (unsigned char*)d_ws;   // uses ~8.02 MB

  egnn_pre<<<NG, 256, 0, stream>>>(x, emb_w, emb_b,
      edge_w1, edge_b1, edge_w2, edge_b2, coord_w1, coord_b1, ws);
  egnn_edge_main<<<4*NG, 256, 0, stream>>>(x, edge_w1, edge_b2, coord_w2,
      out, ws);
  egnn_node_mfma<<<NG, 256, 0, stream>>>(x, emb_w, emb_b,
      node_w1, node_b1, node_w2, node_b2, final_w, final_b,
      out, (const float*)ws);
}

// Round 14
// 73.604 us; speedup vs baseline: 3.4296x; 1.0547x over previous
//
#include <hip/hip_runtime.h>

// EquivariantGNN: 256 graphs, N=64 nodes, HID=64, fp32 in/out.
// R14: dual-node ILP. R13 was latency-stalled at ~50% issue (VALU 38 + MFMA 12)
// with clean traffic. Each wave now interleaves TWO independent nodes (i0,i1):
// one c8 / b3 / b2 / sPX read feeds both chains; abb cvt hoisted to f32 per
// pair. No launch-bounds min-waves (R8/9/10/12: always catastrophic).

#define NG 256

typedef __attribute__((ext_vector_type(4))) float f32x4;
typedef __attribute__((ext_vector_type(8))) __bf16 bf16x8;

__device__ __forceinline__ f32x4 mfma16(bf16x8 a, bf16x8 b, f32x4 c){
  return __builtin_amdgcn_mfma_f32_16x16x32_bf16(a, b, c, 0, 0, 0);
}

// ws layout (bytes):
//   [0, 4M)            mi        f32 [256][64][64]
//   [4M, 6M)           a+b1      bf16 [256][64][64]
//   [6M, 8M)           c         bf16 [256][64][64]
//   [8M, 8M+8K)        W3^T      bf16 [64][64]   ([n'][k])
//   [8M+8K, 8M+16K)    W2^T      bf16 [64][64]   ([n][k])
//   [8M+16K, +256B)    cb1'      f32 [64]
#define WS_A   (4u<<20)
#define WS_C   (6u<<20)
#define WS_W3  (8u<<20)
#define WS_W2  ((8u<<20)+8192u)
#define WS_CB1 ((8u<<20)+16384u)

__global__ __launch_bounds__(256)
void egnn_pre(const float* __restrict__ x,
    const float* __restrict__ emb_w,  const float* __restrict__ emb_b,
    const float* __restrict__ edge_w1,const float* __restrict__ edge_b1,
    const float* __restrict__ edge_w2,const float* __restrict__ edge_b2,
    const float* __restrict__ coord_w1,const float* __restrict__ coord_b1,
    unsigned char* __restrict__ ws)
{
  __shared__ __align__(16) float sHt[64*64];   // h^T [m][i]
  __shared__ __align__(16) float sW [64*65];   // staged weight (padded)
  __shared__ float sXL[384], sEW[384], sEB[64], sB1[64];

  const int bs = blockIdx.x, tid = threadIdx.x;
  const float* xg = x + bs*384;
  __bf16* wsa = (__bf16*)(ws + WS_A) + bs*4096;
  __bf16* wsc = (__bf16*)(ws + WS_C) + bs*4096;

  for (int q=tid; q<384; q+=256){ sXL[q]=xg[q]; sEW[q]=emb_w[q]; }
  if (tid < 64){ sEB[tid]=emb_b[tid]; sB1[tid]=edge_b1[tid]; }
  __syncthreads();

  // h^T[m][i]
  #pragma unroll
  for (int e=0;e<16;e++){
    int idx=tid+e*256; int m=idx>>6, i=idx&63;
    float v = sEB[m];
    #pragma unroll
    for (int d=0;d<6;d++) v += sXL[i*6+d]*sEW[d*64+m];
    sHt[m*64+i] = v;
  }

  // ---- a = h@W1a + b1 -> bf16 ws ----
  #pragma unroll
  for (int e=0;e<16;e++){ int idx=tid+e*256;
    sW[(idx>>6)*65 + (idx&63)] = edge_w1[idx]; }
  __syncthreads();
  {
    const int tjx = tid>>5, tnx = tid&31;
    #pragma unroll
    for (int rb=0;rb<2;rb++){
      const int i0 = rb*32 + 4*tjx;
      float acc[4][2] = {};
      for (int m=0;m<64;m++){
        float4 av = *(const float4*)&sHt[m*64 + i0];
        float b0 = sW[m*65 + 2*tnx], b1v = sW[m*65 + 2*tnx + 1];
        acc[0][0]+=av.x*b0; acc[0][1]+=av.x*b1v;
        acc[1][0]+=av.y*b0; acc[1][1]+=av.y*b1v;
        acc[2][0]+=av.z*b0; acc[2][1]+=av.z*b1v;
        acc[3][0]+=av.w*b0; acc[3][1]+=av.w*b1v;
      }
      #pragma unroll
      for (int r=0;r<4;r++)
        #pragma unroll
        for (int c=0;c<2;c++)
          wsa[(i0+r)*64 + 2*tnx+c] = (__bf16)(acc[r][c] + sB1[2*tnx+c]);
    }
  }
  __syncthreads();

  // ---- c = h@W1b -> bf16 ws ----
  #pragma unroll
  for (int e=0;e<16;e++){ int idx=tid+e*256;
    sW[(idx>>6)*65 + (idx&63)] = edge_w1[4096 + idx]; }
  __syncthreads();
  {
    const int tjx = tid>>5, tnx = tid&31;
    #pragma unroll
    for (int rb=0;rb<2;rb++){
      const int i0 = rb*32 + 4*tjx;
      float acc[4][2] = {};
      for (int m=0;m<64;m++){
        float4 av = *(const float4*)&sHt[m*64 + i0];
        float b0 = sW[m*65 + 2*tnx], b1v = sW[m*65 + 2*tnx + 1];
        acc[0][0]+=av.x*b0; acc[0][1]+=av.x*b1v;
        acc[1][0]+=av.y*b0; acc[1][1]+=av.y*b1v;
        acc[2][0]+=av.z*b0; acc[2][1]+=av.z*b1v;
        acc[3][0]+=av.w*b0; acc[3][1]+=av.w*b1v;
      }
      #pragma unroll
      for (int r=0;r<4;r++)
        #pragma unroll
        for (int c=0;c<2;c++)
          wsc[(i0+r)*64 + 2*tnx+c] = (__bf16)acc[r][c];
    }
  }

  // ---- block 0 only: graph-invariant W3^T, W2^T, cb1' ----
  if (bs == 0){
    __syncthreads();
    #pragma unroll
    for (int e=0;e<16;e++){ int idx=tid+e*256;
      sW[(idx>>6)*65 + (idx&63)] = coord_w1[idx]; }   // cw1
    __syncthreads();
    {
      // W3[k][c] = sum_n W2[k][n]*cw1[n][c]
      const int k = tid>>2, c0 = (tid&3)*16;
      float acc[16] = {};
      for (int n=0;n<64;n++){
        float w = edge_w2[k*64+n];
        #pragma unroll
        for (int cc=0;cc<16;cc+=4){
          float4 b = *(const float4*)&sW[n*65 + c0+cc];
          acc[cc]+=w*b.x; acc[cc+1]+=w*b.y; acc[cc+2]+=w*b.z; acc[cc+3]+=w*b.w;
        }
      }
      __bf16* w3t = (__bf16*)(ws + WS_W3);
      #pragma unroll
      for (int cc=0;cc<16;cc++) w3t[(c0+cc)*64 + k] = (__bf16)acc[cc];
    }
    { // W2^T
      __bf16* w2t = (__bf16*)(ws + WS_W2);
      #pragma unroll
      for (int e=0;e<16;e++){ int idx=tid+e*256; int n=idx>>6, k=idx&63;
        w2t[idx] = (__bf16)edge_w2[k*64+n]; }
    }
    if (tid < 64){ // cb1' = cb1 + b2@cw1
      float s = coord_b1[tid];
      for (int n=0;n<64;n++) s += edge_b2[n]*sW[n*65 + tid];
      ((float*)(ws + WS_CB1))[tid] = s;
    }
  }
}

__global__ __launch_bounds__(256)
void egnn_edge_main(const float* __restrict__ x,
    const float* __restrict__ edge_w1, const float* __restrict__ edge_b2,
    const float* __restrict__ coord_w2,
    float* __restrict__ out, unsigned char* __restrict__ ws)
{
  __shared__ __align__(16) __bf16 sC  [64*72];
  __shared__ __align__(16) __bf16 sW3t[64*72];
  __shared__ __align__(16) __bf16 sW2t[64*72];
  __shared__ __align__(16) __bf16 sABb[16*72];
  __shared__ float sPX[64], sPY[64], sPZ[64];
  __shared__ __align__(16) float sW1L[64];
  __shared__ float sCB1p[64], sCW2[64], sB2[64];

  const int bx = blockIdx.x, tid = threadIdx.x;
  const int g = bx>>2, quarter = bx&3;
  const int lane = tid&63, wv = tid>>6, lg = lane>>4, ln = lane&15;
  const float* xg = x + g*384;

  // ---- stage ----
  {
    const bf16x8* pc = (const bf16x8*)((__bf16*)(ws + WS_C) + g*4096);
    const bf16x8* p3 = (const bf16x8*)(ws + WS_W3);
    const bf16x8* p2 = (const bf16x8*)(ws + WS_W2);
    const bf16x8* pa = (const bf16x8*)((__bf16*)(ws + WS_A) + g*4096 + quarter*1024);
    #pragma unroll
    for (int e=0;e<2;e++){
      int q = tid + e*256; int row=q>>3, c8=q&7;
      *(bf16x8*)&sC  [row*72 + c8*8] = pc[q];
      *(bf16x8*)&sW3t[row*72 + c8*8] = p3[q];
      *(bf16x8*)&sW2t[row*72 + c8*8] = p2[q];
    }
    if (tid < 128){ int q=tid; int row=q>>3, c8=q&7;
      *(bf16x8*)&sABb[row*72 + c8*8] = pa[q]; }
  }
  if (tid < 64){
    sW1L[tid]  = edge_w1[8192 + tid];
    sCB1p[tid] = ((const float*)(ws + WS_CB1))[tid];
    sCW2[tid]  = coord_w2[tid];
    sB2[tid]   = edge_b2[tid];
    sPX[tid]=xg[tid*6]; sPY[tid]=xg[tid*6+1]; sPZ[tid]=xg[tid*6+2];
  }
  __syncthreads();

  float* ws_mi = (float*)ws;

  // loop-invariant w1L fragment (16 regs)
  float w18[2][8];
  #pragma unroll
  for (int kb=0;kb<2;kb++){
    *(float4*)&w18[kb][0] = *(const float4*)&sW1L[kb*32+lg*8];
    *(float4*)&w18[kb][4] = *(const float4*)&sW1L[kb*32+lg*8+4];
  }

  // ---- main loop: wave wv owns node PAIR (il0, il1) per iteration ----
  #pragma unroll
  for (int p=0; p<2; p++){
    const int il0 = p*8 + wv, il1 = p*8 + 4 + wv;
    const int i0  = quarter*16 + il0, i1 = quarter*16 + il1;
    float dsqv0, dsqv1;
    {
      float dx=sPX[i0]-sPX[lane], dy=sPY[i0]-sPY[lane], dz=sPZ[i0]-sPZ[lane];
      dsqv0 = dx*dx+dy*dy+dz*dz;
      dx=sPX[i1]-sPX[lane]; dy=sPY[i1]-sPY[lane]; dz=sPZ[i1]-sPZ[lane];
      dsqv1 = dx*dx+dy*dy+dz*dz;
    }
    // a+b1 rows, hoisted to f32
    float abf0[2][8], abf1[2][8];
    #pragma unroll
    for (int kb=0;kb<2;kb++){
      bf16x8 t0 = *(const bf16x8*)&sABb[il0*72 + kb*32 + lg*8];
      bf16x8 t1 = *(const bf16x8*)&sABb[il1*72 + kb*32 + lg*8];
      #pragma unroll
      for (int e=0;e<8;e++){ abf0[kb][e]=(float)t0[e]; abf1[kb][e]=(float)t1[e]; }
    }
    f32x4 accm0[4], accm1[4];
    #pragma unroll
    for (int nt=0;nt<4;nt++){
      accm0[nt] = f32x4{0.f,0.f,0.f,0.f};
      accm1[nt] = f32x4{0.f,0.f,0.f,0.f};
    }
    float sw0=0.f, swx0=0.f, swy0=0.f, swz0=0.f;
    float sw1=0.f, swx1=0.f, swy1=0.f, swz1=0.f;

    #pragma unroll
    for (int jt=0;jt<4;jt++){
      const int j = jt*16 + ln;
      const float dq0 = __shfl(dsqv0, j);
      const float dq1 = __shfl(dsqv1, j);
      f32x4 a40[4], a41[4];
      #pragma unroll
      for (int nt=0;nt<4;nt++){
        a40[nt] = f32x4{0.f,0.f,0.f,0.f};
        a41[nt] = f32x4{0.f,0.f,0.f,0.f};
      }

      #pragma unroll
      for (int kb=0;kb<2;kb++){
        const int k0 = kb*32 + lg*8;
        bf16x8 c8 = *(const bf16x8*)&sC[j*72 + k0];   // shared by both nodes
        bf16x8 t80, t81;
        #pragma unroll
        for (int e=0;e<8;e++){
          float cf = (float)c8[e];
          float v0 = fmaxf(fmaf(dq0, w18[kb][e], abf0[kb][e] + cf), 0.f);
          float v1 = fmaxf(fmaf(dq1, w18[kb][e], abf1[kb][e] + cf), 0.f);
          t80[e] = (__bf16)v0;
          t81[e] = (__bf16)v1;
        }
        #pragma unroll
        for (int nt=0;nt<4;nt++){
          bf16x8 b3 = *(const bf16x8*)&sW3t[(nt*16+ln)*72 + k0];  // shared
          a40[nt] = mfma16(t80, b3, a40[nt]);
          a41[nt] = mfma16(t81, b3, a41[nt]);
        }
        #pragma unroll
        for (int nt=0;nt<4;nt++){
          bf16x8 b2 = *(const bf16x8*)&sW2t[(nt*16+ln)*72 + k0];  // shared
          accm0[nt] = mfma16(t80, b2, accm0[nt]);
          accm1[nt] = mfma16(t81, b2, accm1[nt]);
        }
      }

      // deferred epilogue: per-lane partials for both nodes (shared LDS reads)
      #pragma unroll
      for (int r=0;r<4;r++){
        float p0 = 0.f, p1 = 0.f;
        #pragma unroll
        for (int nt=0;nt<4;nt++){
          int n = nt*16 + ln;
          float cb = sCB1p[n], cw = sCW2[n];
          p0 += fmaxf(a40[nt][r] + cb, 0.f)*cw;
          p1 += fmaxf(a41[nt][r] + cb, 0.f)*cw;
        }
        int jj = jt*16 + lg*4 + r;
        float px = sPX[jj], py = sPY[jj], pz = sPZ[jj];
        sw0 += p0; swx0 += p0*px; swy0 += p0*py; swz0 += p0*pz;
        sw1 += p1; swx1 += p1*px; swy1 += p1*py; swz1 += p1*pz;
      }
    }

    // m_i for both nodes
    #pragma unroll
    for (int nt=0;nt<4;nt++){
      float s0 = accm0[nt][0]+accm0[nt][1]+accm0[nt][2]+accm0[nt][3];
      float s1 = accm1[nt][0]+accm1[nt][1]+accm1[nt][2]+accm1[nt][3];
      s0 += __shfl_xor(s0,16); s0 += __shfl_xor(s0,32);
      s1 += __shfl_xor(s1,16); s1 += __shfl_xor(s1,32);
      if (lg == 0){
        int n = nt*16 + ln;
        float b2n = 64.f*sB2[n];
        ws_mi[(g*64 + i0)*64 + n] = s0 + b2n;
        ws_mi[(g*64 + i1)*64 + n] = s1 + b2n;
      }
    }

    // pos butterflies (both nodes)
    #pragma unroll
    for (int off=1; off<64; off<<=1){
      sw0  += __shfl_xor(sw0, off);  swx0 += __shfl_xor(swx0, off);
      swy0 += __shfl_xor(swy0, off); swz0 += __shfl_xor(swz0, off);
      sw1  += __shfl_xor(sw1, off);  swx1 += __shfl_xor(swx1, off);
      swy1 += __shfl_xor(swy1, off); swz1 += __shfl_xor(swz1, off);
    }
    if (lane == 0){
      float* o0 = out + (g*64 + i0)*6;
      o0[0] = sPX[i0] + (sPX[i0]*sw0 - swx0)*(1.f/64.f);
      o0[1] = sPY[i0] + (sPY[i0]*sw0 - swy0)*(1.f/64.f);
      o0[2] = sPZ[i0] + (sPZ[i0]*sw0 - swz0)*(1.f/64.f);
      float* o1 = out + (g*64 + i1)*6;
      o1[0] = sPX[i1] + (sPX[i1]*sw1 - swx1)*(1.f/64.f);
      o1[1] = sPY[i1] + (sPY[i1]*sw1 - swy1)*(1.f/64.f);
      o1[2] = sPZ[i1] + (sPZ[i1]*sw1 - swz1)*(1.f/64.f);
    }
  }
}

// Node kernel: z = relu([h|mi]@nw1+nb1) via MFMA (K=128);
// vel_out = vel + h@fw3 + z@(nw2@fw3) + (nb2@fw3 + fb3).
__global__ __launch_bounds__(256)
void egnn_node_mfma(const float* __restrict__ x,
    const float* __restrict__ emb_w,  const float* __restrict__ emb_b,
    const float* __restrict__ node_w1,const float* __restrict__ node_b1,
    const float* __restrict__ node_w2,const float* __restrict__ node_b2,
    const float* __restrict__ final_w,const float* __restrict__ final_b,
    float* __restrict__ out, const float* __restrict__ ws_mi)
{
  __shared__ __align__(16) float  sHt [64*64];
  __shared__ __align__(16) __bf16 sAb [64*136];
  __shared__ __align__(16) __bf16 sNW1t[64*136];
  __shared__ __align__(16) float sNW2[64*64];
  __shared__ float sG  [64*4];
  __shared__ float sHf3[64*4];
  __shared__ float sFW3[64*4];
  __shared__ float sCvec[4];
  __shared__ float sXL[384], sEW[384], sEB[64], sNB1[64], sNB2[64];

  const int bs=blockIdx.x, tid=threadIdx.x;
  const int lane=tid&63, wv=tid>>6, ln=lane&15, lg=lane>>4;
  const float* xg = x + bs*384;

  for (int q=tid;q<384;q+=256){ sXL[q]=xg[q]; sEW[q]=emb_w[q]; }
  if (tid<64){ sEB[tid]=emb_b[tid]; sNB1[tid]=node_b1[tid]; sNB2[tid]=node_b2[tid]; }
  if (tid<192){ int n=tid&63, d=tid>>6; sFW3[n*4+d]=final_w[n*6+3+d]; }
  { const float4* g2=(const float4*)node_w2; float4* d2=(float4*)sNW2;
    #pragma unroll
    for (int e=0;e<4;e++) d2[tid+e*256]=g2[tid+e*256]; }
  #pragma unroll
  for (int e=0;e<32;e++){ int idx=tid+e*256; int kk=idx>>6, n=idx&63;
    sNW1t[n*136+kk]=(__bf16)node_w1[idx]; }
  { const float* mig = ws_mi + bs*4096;
    #pragma unroll
    for (int e=0;e<16;e++){ int idx=tid+e*256; int i=idx>>6, n=idx&63;
      sAb[i*136+64+n]=(__bf16)mig[idx]; } }
  __syncthreads();

  { int j=tid&63, mb=tid>>6;
    #pragma unroll
    for (int mm=0;mm<16;mm++){ int m=mb*16+mm;
      float v=sEB[m];
      #pragma unroll
      for (int d=0;d<6;d++) v+=sXL[j*6+d]*sEW[d*64+m];
      sHt[m*64+j]=v; sAb[j*136+m]=(__bf16)v; } }
  __syncthreads();

  if (tid<192){
    int k=tid&63, d=tid>>6;
    float gacc=0.f, s=0.f;
    for (int nn=0;nn<64;nn++){
      int n=(nn+k)&63;
      gacc += sNW2[k*64+n]*sFW3[n*4+d];
      s    += sHt[nn*64+k]*sFW3[nn*4+d];
    }
    sG[k*4+d]=gacc; sHf3[k*4+d]=s;
  } else if (tid<195){
    int d=tid-192; float c=final_b[3+d];
    for (int n=0;n<64;n++) c+=sNB2[n]*sFW3[n*4+d];
    sCvec[d]=c;
  }
  __syncthreads();

  f32x4 acc[4];
  #pragma unroll
  for (int nt=0;nt<4;nt++) acc[nt]=f32x4{0.f,0.f,0.f,0.f};
  #pragma unroll
  for (int kb=0;kb<4;kb++){
    bf16x8 a8 = *(const bf16x8*)&sAb[(wv*16+ln)*136 + kb*32 + lg*8];
    #pragma unroll
    for (int nt=0;nt<4;nt++){
      bf16x8 b8 = *(const bf16x8*)&sNW1t[(nt*16+ln)*136 + kb*32 + lg*8];
      acc[nt]=mfma16(a8,b8,acc[nt]);
    }
  }
  float p[4][3];
  #pragma unroll
  for(int r=0;r<4;r++){ p[r][0]=0.f; p[r][1]=0.f; p[r][2]=0.f; }
  #pragma unroll
  for (int nt=0;nt<4;nt++){
    int n=nt*16+ln;
    float zb=sNB1[n];
    float g0=sG[n*4], g1=sG[n*4+1], g2=sG[n*4+2];
    #pragma unroll
    for (int r=0;r<4;r++){
      float u=fmaxf(acc[nt][r]+zb,0.f);
      p[r][0]+=u*g0; p[r][1]+=u*g1; p[r][2]+=u*g2;
    }
  }
  #pragma unroll
  for (int off=1;off<16;off<<=1)
    #pragma unroll
    for (int r=0;r<4;r++){
      p[r][0]+=__shfl_xor(p[r][0],off);
      p[r][1]+=__shfl_xor(p[r][1],off);
      p[r][2]+=__shfl_xor(p[r][2],off);
    }
  if (ln==0){
    #pragma unroll
    for (int r=0;r<4;r++){
      int j=wv*16+lg*4+r; int base=(bs*64+j)*6;
      #pragma unroll
      for (int d=0;d<3;d++)
        out[base+3+d]=xg[j*6+3+d]+sHf3[j*4+d]+sCvec[d]+p[r][d];
    }
  }
}

extern "C" void kernel_launch(void* const* d_in, const int* in_sizes, int n_in,
                              void* d_out, int out_size, void* d_ws, size_t ws_size,
                              hipStream_t stream)
{
  const float* x        = (const float*)d_in[0];
  const float* emb_w    = (const float*)d_in[1];
  const float* emb_b    = (const float*)d_in[2];
  const float* edge_w1  = (const float*)d_in[3];
  const float* edge_b1  = (const float*)d_in[4];
  const float* edge_w2  = (const float*)d_in[5];
  const float* edge_b2  = (const float*)d_in[6];
  const float* node_w1  = (const float*)d_in[7];
  const float* node_b1  = (const float*)d_in[8];
  const float* node_w2  = (const float*)d_in[9];
  const float* node_b2  = (const float*)d_in[10];
  const float* coord_w1 = (const float*)d_in[11];
  const float* coord_b1 = (const float*)d_in[12];
  const float* coord_w2 = (const float*)d_in[13];
  const float* final_w  = (const float*)d_in[14];
  const float* final_b  = (const float*)d_in[15];
  float* out = (float*)d_out;
  unsigned char* ws = (unsigned char*)d_ws;   // uses ~8.02 MB

  egnn_pre<<<NG, 256, 0, stream>>>(x, emb_w, emb_b,
      edge_w1, edge_b1, edge_w2, edge_b2, coord_w1, coord_b1, ws);
  egnn_edge_main<<<4*NG, 256, 0, stream>>>(x, edge_w1, edge_b2, coord_w2,
      out, ws);
  egnn_node_mfma<<<NG, 256, 0, stream>>>(x, emb_w, emb_b,
      node_w1, node_b1, node_w2, node_b2, final_w, final_b,
      out, (const float*)ws);
}